// Round 8
// baseline (390.821 us; speedup 1.0000x reference)
//
#include <hip/hip_runtime.h>

#define D 128
#define NLAYERS 4

typedef unsigned short ushort_t;
typedef unsigned int uint_t;
typedef __attribute__((ext_vector_type(8))) short short8;   // 8 bf16 = 4 VGPR
typedef __attribute__((ext_vector_type(4))) float f32x4;    // mfma accumulator

// round-to-nearest-even fp32 -> bf16 (values are finite; NaN path not needed)
__device__ __forceinline__ ushort_t f2bf(float f) {
    uint_t u = __float_as_uint(f);
    u += 0x7FFFu + ((u >> 16) & 1u);
    return (ushort_t)(u >> 16);
}
__device__ __forceinline__ float bf_lo(uint_t u) {  // low ushort -> float
    return __uint_as_float(u << 16);
}
__device__ __forceinline__ float bf_hi(uint_t u) {  // high ushort -> float
    return __uint_as_float(u & 0xFFFF0000u);
}
__device__ __forceinline__ uint_t pack2(float a, float b) {
    return (uint_t)f2bf(a) | ((uint_t)f2bf(b) << 16);
}

// ---------------- CSR build ----------------

__global__ void k_count_deg(const int* __restrict__ dsts, int E,
                            int* __restrict__ deg, int* __restrict__ slot) {
    int i = blockIdx.x * blockDim.x + threadIdx.x;
    if (i < E) slot[i] = atomicAdd(&deg[dsts[i]], 1);
}

// exclusive scan of padded row lengths plen=(deg+1 rounded up to 4) -> prow,
// plus dinv = rsqrt(deg+1) (fused). 1024 elems per 256-thread block.
__global__ void k_scan1(const int* __restrict__ deg, int n, int* __restrict__ prow,
                        int* __restrict__ partials, float* __restrict__ dinv) {
    __shared__ int wsum[4];
    int tid = threadIdx.x;
    int base = blockIdx.x * 1024 + tid * 4;
    int g0 = (base + 0 < n) ? deg[base + 0] : -4;   // -4 -> plen 0 for oob
    int g1 = (base + 1 < n) ? deg[base + 1] : -4;
    int g2 = (base + 2 < n) ? deg[base + 2] : -4;
    int g3 = (base + 3 < n) ? deg[base + 3] : -4;
    if (base + 0 < n) dinv[base + 0] = rsqrtf((float)(g0 + 1));
    if (base + 1 < n) dinv[base + 1] = rsqrtf((float)(g1 + 1));
    if (base + 2 < n) dinv[base + 2] = rsqrtf((float)(g2 + 1));
    if (base + 3 < n) dinv[base + 3] = rsqrtf((float)(g3 + 1));
    int p0 = (g0 + 4) & ~3;   // padded length, multiple of 4 (includes self)
    int p1 = (g1 + 4) & ~3;
    int p2 = (g2 + 4) & ~3;
    int p3 = (g3 + 4) & ~3;
    int s = p0 + p1 + p2 + p3;
    int lane = tid & 63;
    int incl = s;
    #pragma unroll
    for (int off = 1; off < 64; off <<= 1) {
        int y = __shfl_up(incl, off);
        if (lane >= off) incl += y;
    }
    int wid = tid >> 6;
    if (lane == 63) wsum[wid] = incl;
    __syncthreads();
    int wprev = 0;
    for (int w = 0; w < wid; w++) wprev += wsum[w];
    int excl = wprev + (incl - s);
    if (base + 0 < n) prow[base + 0] = excl;
    if (base + 1 < n) prow[base + 1] = excl + p0;
    if (base + 2 < n) prow[base + 2] = excl + p0 + p1;
    if (base + 3 < n) prow[base + 3] = excl + p0 + p1 + p2;
    if (tid == 255) partials[blockIdx.x] = wprev + incl;
}

// add cross-block prefix (serial <=49 adds, block-uniform) + write prow[n]
__global__ void k_scan23(int* __restrict__ prow, const int* __restrict__ partials,
                         int n, int nb) {
    int i = blockIdx.x * blockDim.x + threadIdx.x;
    int chunk = (blockIdx.x * blockDim.x) >> 10;   // uniform per block
    int pre = 0;
    for (int j = 0; j < chunk; j++) pre += partials[j];
    if (i < n) prow[i] += pre;
    if (i == 0) {
        int tot = 0;
        for (int j = 0; j < nb; j++) tot += partials[j];
        prow[n] = tot;
    }
}

// ---------------- merged prep: place + self/pad + x->xs convert + W prep + zero row ----------------
// xs = bf16(dinv * x); ewi[prow[c]] = c (self), edges at +1+slot, pads -> node n (zero row)
__global__ void k_prep(const int* __restrict__ srcs, const int* __restrict__ dsts,
                       const int* __restrict__ deg, const int* __restrict__ slot,
                       const int* __restrict__ prow, const float* __restrict__ dinv,
                       const float* __restrict__ x, const float* __restrict__ W,
                       int* __restrict__ ewi, ushort_t* __restrict__ xs0,
                       ushort_t* __restrict__ xs1, ushort_t* __restrict__ Wt_hi,
                       ushort_t* __restrict__ Wt_lo, int n, int E,
                       int B1, int B2, int B3, int B4) {
    int b = blockIdx.x;
    int tid = threadIdx.x;
    if (b < B1) {                          // edge placement
        int i = b * 256 + tid;
        if (i < E) {
            int c = dsts[i];
            ewi[prow[c] + 1 + slot[i]] = srcs[i];
        }
    } else if (b < B2) {                   // self + pad fill
        int i = (b - B1) * 256 + tid;
        if (i < n) {
            int base = prow[i];
            int len = deg[i] + 1;
            int plen = (deg[i] + 4) & ~3;
            ewi[base] = i;
            for (int j = len; j < plen; j++) ewi[base + j] = n;
        }
    } else if (b < B3) {                   // xs0 = bf16(dinv * x), 4 floats/thread
        int idx = (b - B2) * 256 + tid;    // total4 = n*D/4
        if (idx < n * (D / 4)) {
            int row = idx >> 5;            // idx*4 / 128
            float di = dinv[row];
            float4 v = ((const float4*)x)[idx];
            uint2 o;
            o.x = pack2(di * v.x, di * v.y);
            o.y = pack2(di * v.z, di * v.w);
            ((uint2*)xs0)[idx] = o;
        }
    } else if (b < B4) {                   // W transpose + hi/lo split
        int t = (b - B3) * 256 + tid;      // NLAYERS*D*D threads
        int l = t >> 14;
        int k = (t >> 7) & 127;
        int nn = t & 127;
        float w = W[((size_t)l << 14) + k * 128 + nn];
        ushort_t hi = f2bf(w);
        float wf = __uint_as_float((uint_t)hi << 16);
        ushort_t lo = f2bf(w - wf);
        size_t o = ((size_t)l << 14) + nn * 128 + k;
        Wt_hi[o] = hi;
        Wt_lo[o] = lo;
    } else {                               // zero row n of both activation buffers
        if (tid < 128) xs0[(size_t)n * D + tid] = 0;
        else xs1[(size_t)n * D + (tid - 128)] = 0;
    }
}

// ---------------- per-layer: s = dinv * (sum over CSR row of xs[src]) ----------------
// one wave per node; lane group sub=lane>>4 owns 4 consecutive edges via one
// int4 src load; gathers are uint4 (16B) over columns t=(lane&15)*8.
__global__ __launch_bounds__(256) void k_aggregate(
    const ushort_t* __restrict__ xs, const int* __restrict__ prow,
    const int* __restrict__ ewi, const float* __restrict__ dinv,
    ushort_t* __restrict__ s, int n) {
    int gwave = (blockIdx.x * 256 + threadIdx.x) >> 6;
    if (gwave >= n) return;
    int lane = threadIdx.x & 63;
    int sub = lane >> 4;
    int t = lane & 15;
    int node = gwave;
    float di = dinv[node];

    float acc[8] = {0.f, 0.f, 0.f, 0.f, 0.f, 0.f, 0.f, 0.f};
    int e = prow[node], end = prow[node + 1];
    // main: 16 edges per iter; sub's 4 edges via one int4
    for (; e + 16 <= end; e += 16) {
        int4 gg = *(const int4*)(ewi + e + sub * 4);
        uint4 v0 = *(const uint4*)(xs + (size_t)gg.x * D + t * 8);
        uint4 v1 = *(const uint4*)(xs + (size_t)gg.y * D + t * 8);
        uint4 v2 = *(const uint4*)(xs + (size_t)gg.z * D + t * 8);
        uint4 v3 = *(const uint4*)(xs + (size_t)gg.w * D + t * 8);
        acc[0] += bf_lo(v0.x); acc[1] += bf_hi(v0.x);
        acc[2] += bf_lo(v0.y); acc[3] += bf_hi(v0.y);
        acc[4] += bf_lo(v0.z); acc[5] += bf_hi(v0.z);
        acc[6] += bf_lo(v0.w); acc[7] += bf_hi(v0.w);
        acc[0] += bf_lo(v1.x); acc[1] += bf_hi(v1.x);
        acc[2] += bf_lo(v1.y); acc[3] += bf_hi(v1.y);
        acc[4] += bf_lo(v1.z); acc[5] += bf_hi(v1.z);
        acc[6] += bf_lo(v1.w); acc[7] += bf_hi(v1.w);
        acc[0] += bf_lo(v2.x); acc[1] += bf_hi(v2.x);
        acc[2] += bf_lo(v2.y); acc[3] += bf_hi(v2.y);
        acc[4] += bf_lo(v2.z); acc[5] += bf_hi(v2.z);
        acc[6] += bf_lo(v2.w); acc[7] += bf_hi(v2.w);
        acc[0] += bf_lo(v3.x); acc[1] += bf_hi(v3.x);
        acc[2] += bf_lo(v3.y); acc[3] += bf_hi(v3.y);
        acc[4] += bf_lo(v3.z); acc[5] += bf_hi(v3.z);
        acc[6] += bf_lo(v3.w); acc[7] += bf_hi(v3.w);
    }
    // tail: one group of 4 edges per iter (rows are padded to multiples of 4)
    for (; e < end; e += 4) {
        int g = ewi[e + sub];
        uint4 v = *(const uint4*)(xs + (size_t)g * D + t * 8);
        acc[0] += bf_lo(v.x); acc[1] += bf_hi(v.x);
        acc[2] += bf_lo(v.y); acc[3] += bf_hi(v.y);
        acc[4] += bf_lo(v.z); acc[5] += bf_hi(v.z);
        acc[6] += bf_lo(v.w); acc[7] += bf_hi(v.w);
    }
    #pragma unroll
    for (int q = 0; q < 8; q++) {
        acc[q] += __shfl_xor(acc[q], 16);
        acc[q] += __shfl_xor(acc[q], 32);
    }
    if (sub == 0) {
        ushort_t* dst = s + (size_t)node * D + t * 8;
        uint4 o;
        o.x = pack2(di * acc[0], di * acc[1]);
        o.y = pack2(di * acc[2], di * acc[3]);
        o.z = pack2(di * acc[4], di * acc[5]);
        o.w = pack2(di * acc[6], di * acc[7]);
        *(uint4*)dst = o;
    }
}

// ---------------- per-layer: out = relu(A @ W + b), MFMA bf16 ----------------
// non-last layers store xs_next = bf16(dinv * relu); last layer stores fp32 relu.
__global__ __launch_bounds__(256) void k_gemm_mfma(
    const ushort_t* __restrict__ A, const ushort_t* __restrict__ Wt_hi,
    const ushort_t* __restrict__ Wt_lo, const float* __restrict__ bias,
    const float* __restrict__ dinv, float* __restrict__ out_f32,
    ushort_t* __restrict__ out_bf, int n) {
    int tid = threadIdx.x;
    int wave = tid >> 6;
    int lane = tid & 63;
    int lg = lane >> 4;      // k-group / C row-group
    int lr = lane & 15;      // A row / B,C col
    int base_row = blockIdx.x * 128 + wave * 32;

    short8 a[2][4];
    #pragma unroll
    for (int st = 0; st < 2; st++) {
        int r = base_row + st * 16 + lr;
        if (r > n - 1) r = n - 1;
        const ushort_t* ap = A + (size_t)r * D + lg * 8;
        #pragma unroll
        for (int k0 = 0; k0 < 4; k0++)
            a[st][k0] = *(const short8*)(ap + k0 * 32);
    }

    f32x4 acc[2][8];
    #pragma unroll
    for (int st = 0; st < 2; st++)
        #pragma unroll
        for (int nt = 0; nt < 8; nt++)
            acc[st][nt] = (f32x4){0.f, 0.f, 0.f, 0.f};

    #pragma unroll
    for (int nt = 0; nt < 8; nt++) {
        const ushort_t* wh = Wt_hi + (size_t)(nt * 16 + lr) * D + lg * 8;
        const ushort_t* wl = Wt_lo + (size_t)(nt * 16 + lr) * D + lg * 8;
        #pragma unroll
        for (int k0 = 0; k0 < 4; k0++) {
            short8 bh = *(const short8*)(wh + k0 * 32);
            short8 bl = *(const short8*)(wl + k0 * 32);
            acc[0][nt] = __builtin_amdgcn_mfma_f32_16x16x32_bf16(a[0][k0], bh, acc[0][nt], 0, 0, 0);
            acc[0][nt] = __builtin_amdgcn_mfma_f32_16x16x32_bf16(a[0][k0], bl, acc[0][nt], 0, 0, 0);
            acc[1][nt] = __builtin_amdgcn_mfma_f32_16x16x32_bf16(a[1][k0], bh, acc[1][nt], 0, 0, 0);
            acc[1][nt] = __builtin_amdgcn_mfma_f32_16x16x32_bf16(a[1][k0], bl, acc[1][nt], 0, 0, 0);
        }
    }

    #pragma unroll
    for (int nt = 0; nt < 8; nt++) {
        int col = nt * 16 + lr;
        float bv = bias[col];
        #pragma unroll
        for (int st = 0; st < 2; st++) {
            #pragma unroll
            for (int r = 0; r < 4; r++) {
                int grow = base_row + st * 16 + lg * 4 + r;
                if (grow < n) {
                    float o = fmaxf(acc[st][nt][r] + bv, 0.f);
                    if (out_bf) out_bf[(size_t)grow * D + col] = f2bf(dinv[grow] * o);
                    else out_f32[(size_t)grow * D + col] = o;
                }
            }
        }
    }
}

// ---------------- host launch ----------------

extern "C" void kernel_launch(void* const* d_in, const int* in_sizes, int n_in,
                              void* d_out, int out_size, void* d_ws, size_t ws_size,
                              hipStream_t stream) {
    const float* x   = (const float*)d_in[0];
    const int* eidx  = (const int*)d_in[1];
    const float* W   = (const float*)d_in[4];
    const float* b   = (const float*)d_in[5];
    float* out       = (float*)d_out;

    const int N = in_sizes[0] / D;
    const int E = in_sizes[1] / 2;
    const int* srcs = eidx;       // edge_index[0]
    const int* dsts = eidx + E;   // edge_index[1]

    // workspace carve-up (512B aligned)
    char* ws = (char*)d_ws;
    size_t off = 0;
    auto alloc = [&](size_t bytes) -> void* {
        void* p = ws + off;
        off = (off + bytes + 511) & ~(size_t)511;
        return p;
    };
    int*      deg      = (int*)alloc((size_t)N * 4);
    float*    dinv     = (float*)alloc((size_t)N * 4);
    int*      prow     = (int*)alloc((size_t)(N + 1) * 4);
    int*      partials = (int*)alloc(256 * 4);
    int*      ewi      = (int*)alloc((size_t)(E + 4 * N) * 4);   // padded CSR srcs
    ushort_t* s_buf    = (ushort_t*)alloc((size_t)N * D * 2);
    ushort_t* xh0      = (ushort_t*)alloc(((size_t)N + 1) * D * 2);  // +1 zero row
    ushort_t* xh1      = (ushort_t*)alloc(((size_t)N + 1) * D * 2);
    ushort_t* wt_hi    = (ushort_t*)alloc((size_t)NLAYERS * D * D * 2);
    ushort_t* wt_lo    = (ushort_t*)alloc((size_t)NLAYERS * D * D * 2);
    // slot[] only live during CSR build, before first aggregate writes s_buf
    int*      slot     = (int*)s_buf;   // E*4 = 3.2MB <= N*D*2 = 12.8MB
    (void)ws_size; (void)n_in; (void)out_size;

    hipMemsetAsync(deg, 0, (size_t)N * 4, stream);

    int tE = (E + 255) / 256;
    int tN = (N + 255) / 256;
    int nbScan = (N + 1023) / 1024;

    k_count_deg<<<tE, 256, 0, stream>>>(dsts, E, deg, slot);
    k_scan1<<<nbScan, 256, 0, stream>>>(deg, N, prow, partials, dinv);
    k_scan23<<<tN, 256, 0, stream>>>(prow, partials, N, nbScan);

    int B1 = tE;
    int B2 = B1 + tN;
    int B3 = B2 + (N * (D / 4) + 255) / 256;
    int B4 = B3 + (NLAYERS * D * D) / 256;
    k_prep<<<B4 + 1, 256, 0, stream>>>(srcs, dsts, deg, slot, prow, dinv, x, W,
                                       ewi, xh0, xh1, wt_hi, wt_lo, N, E,
                                       B1, B2, B3, B4);

    int aggBlocks = (N + 3) / 4;            // 4 waves (nodes) per 256-thread block
    int gemmBlocks = (N + 127) / 128;       // 128 rows per block (4 waves x 32)

    // activations ping-pong in bf16 (pre-scaled by dinv): xh0 -> xh1 -> xh0 -> xh1
    const ushort_t* xin = xh0;
    for (int l = 0; l < NLAYERS; l++) {
        k_aggregate<<<aggBlocks, 256, 0, stream>>>(xin, prow, ewi, dinv, s_buf, N);
        bool last = (l == NLAYERS - 1);
        ushort_t* xout = last ? nullptr : ((l & 1) ? xh0 : xh1);
        k_gemm_mfma<<<gemmBlocks, 256, 0, stream>>>(
            s_buf, wt_hi + (size_t)l * D * D, wt_lo + (size_t)l * D * D,
            b + (size_t)l * D, dinv, last ? out : nullptr, xout, N);
        xin = xout;
    }
}

// Round 9
// 372.842 us; speedup vs baseline: 1.0482x; 1.0482x over previous
//
#include <hip/hip_runtime.h>

#define D 128
#define NLAYERS 4

typedef unsigned short ushort_t;
typedef unsigned int uint_t;
typedef __attribute__((ext_vector_type(8))) short short8;   // 8 bf16 = 4 VGPR
typedef __attribute__((ext_vector_type(4))) float f32x4;    // mfma accumulator

// round-to-nearest-even fp32 -> bf16 (values are finite; NaN path not needed)
__device__ __forceinline__ ushort_t f2bf(float f) {
    uint_t u = __float_as_uint(f);
    u += 0x7FFFu + ((u >> 16) & 1u);
    return (ushort_t)(u >> 16);
}
__device__ __forceinline__ float bf_lo(uint_t u) {  // low ushort -> float
    return __uint_as_float(u << 16);
}
__device__ __forceinline__ float bf_hi(uint_t u) {  // high ushort -> float
    return __uint_as_float(u & 0xFFFF0000u);
}
__device__ __forceinline__ uint_t pack2(float a, float b) {
    return (uint_t)f2bf(a) | ((uint_t)f2bf(b) << 16);
}

// ---------------- CSR build ----------------

__global__ void k_count_deg(const int* __restrict__ dsts, int E,
                            int* __restrict__ deg, int* __restrict__ slot) {
    int i = blockIdx.x * blockDim.x + threadIdx.x;
    if (i < E) slot[i] = atomicAdd(&deg[dsts[i]], 1);
}

// exclusive scan of padded row lengths plen=(deg+1 rounded up to 8) -> prow,
// plus dinv = rsqrt(deg+1) (fused). 1024 elems per 256-thread block.
__global__ void k_scan1(const int* __restrict__ deg, int n, int* __restrict__ prow,
                        int* __restrict__ partials, float* __restrict__ dinv) {
    __shared__ int wsum[4];
    int tid = threadIdx.x;
    int base = blockIdx.x * 1024 + tid * 4;
    int g0 = (base + 0 < n) ? deg[base + 0] : -8;   // -8 -> plen 0 for oob
    int g1 = (base + 1 < n) ? deg[base + 1] : -8;
    int g2 = (base + 2 < n) ? deg[base + 2] : -8;
    int g3 = (base + 3 < n) ? deg[base + 3] : -8;
    if (base + 0 < n) dinv[base + 0] = rsqrtf((float)(g0 + 1));
    if (base + 1 < n) dinv[base + 1] = rsqrtf((float)(g1 + 1));
    if (base + 2 < n) dinv[base + 2] = rsqrtf((float)(g2 + 1));
    if (base + 3 < n) dinv[base + 3] = rsqrtf((float)(g3 + 1));
    int p0 = (g0 + 8) & ~7;   // padded length, multiple of 8 (includes self)
    int p1 = (g1 + 8) & ~7;
    int p2 = (g2 + 8) & ~7;
    int p3 = (g3 + 8) & ~7;
    int s = p0 + p1 + p2 + p3;
    int lane = tid & 63;
    int incl = s;
    #pragma unroll
    for (int off = 1; off < 64; off <<= 1) {
        int y = __shfl_up(incl, off);
        if (lane >= off) incl += y;
    }
    int wid = tid >> 6;
    if (lane == 63) wsum[wid] = incl;
    __syncthreads();
    int wprev = 0;
    for (int w = 0; w < wid; w++) wprev += wsum[w];
    int excl = wprev + (incl - s);
    if (base + 0 < n) prow[base + 0] = excl;
    if (base + 1 < n) prow[base + 1] = excl + p0;
    if (base + 2 < n) prow[base + 2] = excl + p0 + p1;
    if (base + 3 < n) prow[base + 3] = excl + p0 + p1 + p2;
    if (tid == 255) partials[blockIdx.x] = wprev + incl;
}

// add cross-block prefix (serial <=49 adds, block-uniform) + write prow[n]
__global__ void k_scan23(int* __restrict__ prow, const int* __restrict__ partials,
                         int n, int nb) {
    int i = blockIdx.x * blockDim.x + threadIdx.x;
    int chunk = (blockIdx.x * blockDim.x) >> 10;   // uniform per block
    int pre = 0;
    for (int j = 0; j < chunk; j++) pre += partials[j];
    if (i < n) prow[i] += pre;
    if (i == 0) {
        int tot = 0;
        for (int j = 0; j < nb; j++) tot += partials[j];
        prow[n] = tot;
    }
}

// ---------------- merged prep: place + self/pad + x->xs convert + W prep + zero row ----------------
// xs = bf16(dinv * x); ewi[prow[c]] = c (self), edges at +1+slot, pads -> node n (zero row)
__global__ void k_prep(const int* __restrict__ srcs, const int* __restrict__ dsts,
                       const int* __restrict__ deg, const int* __restrict__ slot,
                       const int* __restrict__ prow, const float* __restrict__ dinv,
                       const float* __restrict__ x, const float* __restrict__ W,
                       int* __restrict__ ewi, ushort_t* __restrict__ xs0,
                       ushort_t* __restrict__ xs1, ushort_t* __restrict__ Wt_hi,
                       ushort_t* __restrict__ Wt_lo, int n, int E,
                       int B1, int B2, int B3, int B4) {
    int b = blockIdx.x;
    int tid = threadIdx.x;
    if (b < B1) {                          // edge placement
        int i = b * 256 + tid;
        if (i < E) {
            int c = dsts[i];
            ewi[prow[c] + 1 + slot[i]] = srcs[i];
        }
    } else if (b < B2) {                   // self + pad fill
        int i = (b - B1) * 256 + tid;
        if (i < n) {
            int base = prow[i];
            int len = deg[i] + 1;
            int plen = (deg[i] + 8) & ~7;
            ewi[base] = i;
            for (int j = len; j < plen; j++) ewi[base + j] = n;
        }
    } else if (b < B3) {                   // xs0 = bf16(dinv * x), 4 floats/thread
        int idx = (b - B2) * 256 + tid;    // total4 = n*D/4
        if (idx < n * (D / 4)) {
            int row = idx >> 5;            // idx*4 / 128
            float di = dinv[row];
            float4 v = ((const float4*)x)[idx];
            uint2 o;
            o.x = pack2(di * v.x, di * v.y);
            o.y = pack2(di * v.z, di * v.w);
            ((uint2*)xs0)[idx] = o;
        }
    } else if (b < B4) {                   // W transpose + hi/lo split
        int t = (b - B3) * 256 + tid;      // NLAYERS*D*D threads
        int l = t >> 14;
        int k = (t >> 7) & 127;
        int nn = t & 127;
        float w = W[((size_t)l << 14) + k * 128 + nn];
        ushort_t hi = f2bf(w);
        float wf = __uint_as_float((uint_t)hi << 16);
        ushort_t lo = f2bf(w - wf);
        size_t o = ((size_t)l << 14) + nn * 128 + k;
        Wt_hi[o] = hi;
        Wt_lo[o] = lo;
    } else {                               // zero row n of both activation buffers
        if (tid < 128) xs0[(size_t)n * D + tid] = 0;
        else xs1[(size_t)n * D + (tid - 128)] = 0;
    }
}

// ---------------- per-layer: s = dinv * (sum over CSR row of xs[src]) ----------------
// HALF-WAVE (32 lanes) per node -> 2 independent gather chains per wave (MLP).
// Within a half: sub=(lane>>4)&1 owns 4 consecutive edges via one int4;
// t=lane&15 owns 8 bf16 columns. Rows padded to multiples of 8 -> tail-free.
__global__ __launch_bounds__(256) void k_aggregate(
    const ushort_t* __restrict__ xs, const int* __restrict__ prow,
    const int* __restrict__ ewi, const float* __restrict__ dinv,
    ushort_t* __restrict__ s, int n) {
    int node = (blockIdx.x * 256 + threadIdx.x) >> 5;   // half-wave id
    if (node >= n) return;
    int lane = threadIdx.x & 63;
    int sub = (lane >> 4) & 1;
    int t = lane & 15;
    float di = dinv[node];

    float acc[8] = {0.f, 0.f, 0.f, 0.f, 0.f, 0.f, 0.f, 0.f};
    int e = prow[node], end = prow[node + 1];
    for (; e < end; e += 8) {
        int4 gg = *(const int4*)(ewi + e + sub * 4);
        uint4 v0 = *(const uint4*)(xs + (size_t)gg.x * D + t * 8);
        uint4 v1 = *(const uint4*)(xs + (size_t)gg.y * D + t * 8);
        uint4 v2 = *(const uint4*)(xs + (size_t)gg.z * D + t * 8);
        uint4 v3 = *(const uint4*)(xs + (size_t)gg.w * D + t * 8);
        acc[0] += bf_lo(v0.x); acc[1] += bf_hi(v0.x);
        acc[2] += bf_lo(v0.y); acc[3] += bf_hi(v0.y);
        acc[4] += bf_lo(v0.z); acc[5] += bf_hi(v0.z);
        acc[6] += bf_lo(v0.w); acc[7] += bf_hi(v0.w);
        acc[0] += bf_lo(v1.x); acc[1] += bf_hi(v1.x);
        acc[2] += bf_lo(v1.y); acc[3] += bf_hi(v1.y);
        acc[4] += bf_lo(v1.z); acc[5] += bf_hi(v1.z);
        acc[6] += bf_lo(v1.w); acc[7] += bf_hi(v1.w);
        acc[0] += bf_lo(v2.x); acc[1] += bf_hi(v2.x);
        acc[2] += bf_lo(v2.y); acc[3] += bf_hi(v2.y);
        acc[4] += bf_lo(v2.z); acc[5] += bf_hi(v2.z);
        acc[6] += bf_lo(v2.w); acc[7] += bf_hi(v2.w);
        acc[0] += bf_lo(v3.x); acc[1] += bf_hi(v3.x);
        acc[2] += bf_lo(v3.y); acc[3] += bf_hi(v3.y);
        acc[4] += bf_lo(v3.z); acc[5] += bf_hi(v3.z);
        acc[6] += bf_lo(v3.w); acc[7] += bf_hi(v3.w);
    }
    // combine the 2 edge slots (xor 16 stays within the 32-lane half)
    #pragma unroll
    for (int q = 0; q < 8; q++) acc[q] += __shfl_xor(acc[q], 16);
    if (sub == 0) {
        ushort_t* dst = s + (size_t)node * D + t * 8;
        uint4 o;
        o.x = pack2(di * acc[0], di * acc[1]);
        o.y = pack2(di * acc[2], di * acc[3]);
        o.z = pack2(di * acc[4], di * acc[5]);
        o.w = pack2(di * acc[6], di * acc[7]);
        *(uint4*)dst = o;
    }
}

// ---------------- per-layer: out = relu(A @ W + b), MFMA bf16 ----------------
// non-last layers store xs_next = bf16(dinv * relu); last layer stores fp32 relu.
// Epilogue pairs adjacent columns via shfl_xor(1) -> 4B/8B stores on even lanes.
__global__ __launch_bounds__(256) void k_gemm_mfma(
    const ushort_t* __restrict__ A, const ushort_t* __restrict__ Wt_hi,
    const ushort_t* __restrict__ Wt_lo, const float* __restrict__ bias,
    const float* __restrict__ dinv, float* __restrict__ out_f32,
    ushort_t* __restrict__ out_bf, int n) {
    int tid = threadIdx.x;
    int wave = tid >> 6;
    int lane = tid & 63;
    int lg = lane >> 4;      // k-group / C row-group
    int lr = lane & 15;      // A row / B,C col
    int base_row = blockIdx.x * 128 + wave * 32;

    short8 a[2][4];
    #pragma unroll
    for (int st = 0; st < 2; st++) {
        int r = base_row + st * 16 + lr;
        if (r > n - 1) r = n - 1;
        const ushort_t* ap = A + (size_t)r * D + lg * 8;
        #pragma unroll
        for (int k0 = 0; k0 < 4; k0++)
            a[st][k0] = *(const short8*)(ap + k0 * 32);
    }

    f32x4 acc[2][8];
    #pragma unroll
    for (int st = 0; st < 2; st++)
        #pragma unroll
        for (int nt = 0; nt < 8; nt++)
            acc[st][nt] = (f32x4){0.f, 0.f, 0.f, 0.f};

    #pragma unroll
    for (int nt = 0; nt < 8; nt++) {
        const ushort_t* wh = Wt_hi + (size_t)(nt * 16 + lr) * D + lg * 8;
        const ushort_t* wl = Wt_lo + (size_t)(nt * 16 + lr) * D + lg * 8;
        #pragma unroll
        for (int k0 = 0; k0 < 4; k0++) {
            short8 bh = *(const short8*)(wh + k0 * 32);
            short8 bl = *(const short8*)(wl + k0 * 32);
            acc[0][nt] = __builtin_amdgcn_mfma_f32_16x16x32_bf16(a[0][k0], bh, acc[0][nt], 0, 0, 0);
            acc[0][nt] = __builtin_amdgcn_mfma_f32_16x16x32_bf16(a[0][k0], bl, acc[0][nt], 0, 0, 0);
            acc[1][nt] = __builtin_amdgcn_mfma_f32_16x16x32_bf16(a[1][k0], bh, acc[1][nt], 0, 0, 0);
            acc[1][nt] = __builtin_amdgcn_mfma_f32_16x16x32_bf16(a[1][k0], bl, acc[1][nt], 0, 0, 0);
        }
    }

    #pragma unroll
    for (int nt = 0; nt < 8; nt++) {
        int col = nt * 16 + lr;
        float bv = bias[col];
        #pragma unroll
        for (int st = 0; st < 2; st++) {
            #pragma unroll
            for (int r = 0; r < 4; r++) {
                int grow = base_row + st * 16 + lg * 4 + r;
                float o = fmaxf(acc[st][nt][r] + bv, 0.f);
                float op = __shfl_xor(o, 1);           // partner column value
                if ((lr & 1) == 0 && grow < n) {
                    if (out_bf) {
                        float dsc = dinv[grow];
                        *(uint_t*)(out_bf + (size_t)grow * D + col) = pack2(dsc * o, dsc * op);
                    } else {
                        float2 ov; ov.x = o; ov.y = op;
                        *(float2*)(out_f32 + (size_t)grow * D + col) = ov;
                    }
                }
            }
        }
    }
}

// ---------------- host launch ----------------

extern "C" void kernel_launch(void* const* d_in, const int* in_sizes, int n_in,
                              void* d_out, int out_size, void* d_ws, size_t ws_size,
                              hipStream_t stream) {
    const float* x   = (const float*)d_in[0];
    const int* eidx  = (const int*)d_in[1];
    const float* W   = (const float*)d_in[4];
    const float* b   = (const float*)d_in[5];
    float* out       = (float*)d_out;

    const int N = in_sizes[0] / D;
    const int E = in_sizes[1] / 2;
    const int* srcs = eidx;       // edge_index[0]
    const int* dsts = eidx + E;   // edge_index[1]

    // workspace carve-up (512B aligned)
    char* ws = (char*)d_ws;
    size_t off = 0;
    auto alloc = [&](size_t bytes) -> void* {
        void* p = ws + off;
        off = (off + bytes + 511) & ~(size_t)511;
        return p;
    };
    int*      deg      = (int*)alloc((size_t)N * 4);
    float*    dinv     = (float*)alloc((size_t)N * 4);
    int*      prow     = (int*)alloc((size_t)(N + 1) * 4);
    int*      partials = (int*)alloc(256 * 4);
    int*      ewi      = (int*)alloc((size_t)(E + 8 * N) * 4);   // padded CSR srcs
    ushort_t* s_buf    = (ushort_t*)alloc((size_t)N * D * 2);
    ushort_t* xh0      = (ushort_t*)alloc(((size_t)N + 1) * D * 2);  // +1 zero row
    ushort_t* xh1      = (ushort_t*)alloc(((size_t)N + 1) * D * 2);
    ushort_t* wt_hi    = (ushort_t*)alloc((size_t)NLAYERS * D * D * 2);
    ushort_t* wt_lo    = (ushort_t*)alloc((size_t)NLAYERS * D * D * 2);
    // slot[] only live during CSR build, before first aggregate writes s_buf
    int*      slot     = (int*)s_buf;   // E*4 = 3.2MB <= N*D*2 = 12.8MB
    (void)ws_size; (void)n_in; (void)out_size;

    hipMemsetAsync(deg, 0, (size_t)N * 4, stream);

    int tE = (E + 255) / 256;
    int tN = (N + 255) / 256;
    int nbScan = (N + 1023) / 1024;

    k_count_deg<<<tE, 256, 0, stream>>>(dsts, E, deg, slot);
    k_scan1<<<nbScan, 256, 0, stream>>>(deg, N, prow, partials, dinv);
    k_scan23<<<tN, 256, 0, stream>>>(prow, partials, N, nbScan);

    int B1 = tE;
    int B2 = B1 + tN;
    int B3 = B2 + (N * (D / 4) + 255) / 256;
    int B4 = B3 + (NLAYERS * D * D) / 256;
    k_prep<<<B4 + 1, 256, 0, stream>>>(srcs, dsts, deg, slot, prow, dinv, x, W,
                                       ewi, xh0, xh1, wt_hi, wt_lo, N, E,
                                       B1, B2, B3, B4);

    int aggBlocks = (N + 7) / 8;            // 8 nodes (half-waves) per 256-thr block
    int gemmBlocks = (N + 127) / 128;       // 128 rows per block (4 waves x 32)

    // activations ping-pong in bf16 (pre-scaled by dinv): xh0 -> xh1 -> xh0 -> xh1
    const ushort_t* xin = xh0;
    for (int l = 0; l < NLAYERS; l++) {
        k_aggregate<<<aggBlocks, 256, 0, stream>>>(xin, prow, ewi, dinv, s_buf, N);
        bool last = (l == NLAYERS - 1);
        ushort_t* xout = last ? nullptr : ((l & 1) ? xh0 : xh1);
        k_gemm_mfma<<<gemmBlocks, 256, 0, stream>>>(
            s_buf, wt_hi + (size_t)l * D * D, wt_lo + (size_t)l * D * D,
            b + (size_t)l * D, dinv, last ? out : nullptr, xout, N);
        xin = xout;
    }
}